// Round 1
// baseline (4075.273 us; speedup 1.0000x reference)
//
#include <hip/hip_runtime.h>

typedef _Float16 f16;

#define BB 8
#define SS 1024
#define DD 1024
#define HH 16
#define HD 64
#define NDIST 513   // circular distances 0..512
#define QPB 16      // q rows per block

// LDS budget (static, must stay <= 64 KB):
//   Wl 16*513*4 = 32832  (rel_v bucket weights, fp32 for atomicAdd)
//   Tl 16*513*2 = 16416  (bias table, fp16)
//   Kb 64*66*2  =  8448  (K/V/relk/relv staging, fp16, stride 66 -> 2-way banks on [lane][d])
//   Pb 16*64*2  =  2048  (attention-prob transpose buffer, fp16)
//   Qb 16*64*4  =  4096  (Q tile, fp32 — keeps QK rounding to K-side only)
//   total 63840 B -> 2 blocks/CU
__global__ __launch_bounds__(256, 2)
void circ_attn_kernel(const float* __restrict__ Qg, const float* __restrict__ Kg,
                      const float* __restrict__ Vg, const float* __restrict__ Rk,
                      const float* __restrict__ Rv, float* __restrict__ Out) {
  __shared__ float Wl[QPB][NDIST];
  __shared__ f16   Tl[QPB][NDIST];
  __shared__ f16   Kb[64][66];
  __shared__ f16   Pb[QPB][64];
  __shared__ float Qb[QPB][64];

  const int bid  = blockIdx.x;
  const int b    = bid >> 10;        // / (H * S/QPB) = /1024
  const int h    = (bid >> 6) & 15;
  const int qg   = bid & 63;
  const int q0   = qg * QPB;
  const int tid  = threadIdx.x;
  const int w    = tid >> 6;
  const int lane = tid & 63;
  const int rb   = w * 4;            // this wave's first q-row (4 rows per wave)

  // ---- stage Q tile (fp32) + zero W buckets ----
  for (int i = tid; i < QPB * 64; i += 256) {
    int r = i >> 6, d = i & 63;
    Qb[r][d] = Qg[((size_t)(b * SS + q0 + r)) * DD + h * HD + d];
  }
  for (int i = tid; i < QPB * NDIST; i += 256) (&Wl[0][0])[i] = 0.f;
  __syncthreads();

  // ---- Phase T: bias table T[row][dist] = q_row . rel_pos_k[dist] ----
  for (int cc = 0; cc < 9; ++cc) {
    const int n = (cc == 8) ? (NDIST - 512) : 64;   // last chunk: 1 row
    for (int i = tid; i < n * 64; i += 256) {
      int r = i >> 6, d = i & 63;
      Kb[r][d] = (f16)Rk[((size_t)(cc * 64 + r)) * HD + d];
    }
    __syncthreads();
    if (lane < n) {
      float t0 = 0.f, t1 = 0.f, t2 = 0.f, t3 = 0.f;
      #pragma unroll
      for (int d = 0; d < 64; ++d) {
        float kv = (float)Kb[lane][d];
        t0 += Qb[rb + 0][d] * kv;
        t1 += Qb[rb + 1][d] * kv;
        t2 += Qb[rb + 2][d] * kv;
        t3 += Qb[rb + 3][d] * kv;
      }
      const int dist = cc * 64 + lane;
      Tl[rb + 0][dist] = (f16)t0;
      Tl[rb + 1][dist] = (f16)t1;
      Tl[rb + 2][dist] = (f16)t2;
      Tl[rb + 3][dist] = (f16)t3;
    }
    __syncthreads();
  }

  float acc[4]  = {0.f, 0.f, 0.f, 0.f};   // O[r][lane=dim], unnormalized
  float lsum[4] = {0.f, 0.f, 0.f, 0.f};   // per-lane partial sum of exp

  // ---- main k loop: 16 chunks of 64 keys ----
  for (int kc = 0; kc < 16; ++kc) {
    // stage K chunk (fp16)
    for (int i = tid; i < 64 * 64; i += 256) {
      int r = i >> 6, d = i & 63;
      Kb[r][d] = (f16)Kg[((size_t)(b * SS + kc * 64 + r)) * DD + h * HD + d];
    }
    __syncthreads();
    // scores: lane = local key index
    {
      float s0 = 0.f, s1 = 0.f, s2 = 0.f, s3 = 0.f;
      #pragma unroll
      for (int d = 0; d < 64; ++d) {
        float kv = (float)Kb[lane][d];
        s0 += Qb[rb + 0][d] * kv;
        s1 += Qb[rb + 1][d] * kv;
        s2 += Qb[rb + 2][d] * kv;
        s3 += Qb[rb + 3][d] * kv;
      }
      const int kgl = kc * 64 + lane;
      float sv[4] = {s0, s1, s2, s3};
      #pragma unroll
      for (int r = 0; r < 4; ++r) {
        const int q = q0 + rb + r;
        int j = (q - kgl) & 1023;
        int dist = (j < 1024 - j) ? j : (1024 - j);
        float s = sv[r] * 0.125f + (float)Tl[rb + r][dist];
        float p = __expf(s);              // no max-subtract: |s| <~ 10, fp32-safe
        Pb[rb + r][lane] = (f16)p;
        lsum[r] += p;
        atomicAdd(&Wl[rb + r][dist], p);  // rel_v bucket weight
      }
    }
    __syncthreads();
    // stage V chunk into the same buffer
    for (int i = tid; i < 64 * 64; i += 256) {
      int r = i >> 6, d = i & 63;
      Kb[r][d] = (f16)Vg[((size_t)(b * SS + kc * 64 + r)) * DD + h * HD + d];
    }
    __syncthreads();
    // PV: lane = dim
    #pragma unroll 4
    for (int kk = 0; kk < 64; ++kk) {
      float vv = (float)Kb[kk][lane];
      acc[0] += (float)Pb[rb + 0][kk] * vv;
      acc[1] += (float)Pb[rb + 1][kk] * vv;
      acc[2] += (float)Pb[rb + 2][kk] * vv;
      acc[3] += (float)Pb[rb + 3][kk] * vv;
    }
    __syncthreads();
  }

  // ---- Phase 5: rel_v contribution via W buckets: acc += W @ rel_v ----
  for (int cc = 0; cc < 9; ++cc) {
    const int n = (cc == 8) ? (NDIST - 512) : 64;
    for (int i = tid; i < n * 64; i += 256) {
      int r = i >> 6, d = i & 63;
      Kb[r][d] = (f16)Rv[((size_t)(cc * 64 + r)) * HD + d];
    }
    __syncthreads();
    for (int kk = 0; kk < n; ++kk) {
      float vv = (float)Kb[kk][lane];
      const int dist = cc * 64 + kk;
      acc[0] += Wl[rb + 0][dist] * vv;
      acc[1] += Wl[rb + 1][dist] * vv;
      acc[2] += Wl[rb + 2][dist] * vv;
      acc[3] += Wl[rb + 3][dist] * vv;
    }
    __syncthreads();
  }

  // ---- finalize: normalize by sum of exp, write out ----
  #pragma unroll
  for (int r = 0; r < 4; ++r) {
    float t = lsum[r];
    #pragma unroll
    for (int off = 32; off > 0; off >>= 1) t += __shfl_xor(t, off, 64);
    const int q = q0 + rb + r;
    Out[((size_t)(b * SS + q)) * DD + h * HD + lane] = acc[r] / t;
  }
}

extern "C" void kernel_launch(void* const* d_in, const int* in_sizes, int n_in,
                              void* d_out, int out_size, void* d_ws, size_t ws_size,
                              hipStream_t stream) {
  const float* q  = (const float*)d_in[0];
  const float* k  = (const float*)d_in[1];
  const float* v  = (const float*)d_in[2];
  const float* rk = (const float*)d_in[3];
  const float* rv = (const float*)d_in[4];
  float* out = (float*)d_out;
  const int nblocks = BB * HH * (SS / QPB);  // 8192
  circ_attn_kernel<<<dim3(nblocks), dim3(256), 0, stream>>>(q, k, v, rk, rv, out);
}

// Round 2
// 803.251 us; speedup vs baseline: 5.0735x; 5.0735x over previous
//
#include <hip/hip_runtime.h>

typedef _Float16 f16;
typedef __attribute__((ext_vector_type(4))) _Float16 f16x4;
typedef __attribute__((ext_vector_type(8))) _Float16 f16x8;
typedef __attribute__((ext_vector_type(4))) float f32x4;

#define BB 8
#define SS 1024
#define DD 1024
#define HH 16
#define HD 64
#define QPB 16
#define PSTR 1032   // P row stride (f16): 2064 B, 16B-aligned, 2-way banks on b128 reads
#define TSTR 520    // T/W row stride (f16): 1040 B, 16B-aligned
#define KSTR 72     // K/Rk/Q staging stride: 144 B rows -> b128 frag reads 2-way
#define VSTR 68     // V/Rv staging stride: scalar key-gather conflict-free (2-way worst)

// LDS: Pf 33024 + Tb 16640 + Sb 9216 + Qb 2304 + lsw 256 = 61440 B -> 2 blocks/CU
__global__ __launch_bounds__(256, 2)
void circ_attn_mfma(const float* __restrict__ Qg, const float* __restrict__ Kg,
                    const float* __restrict__ Vg, const float* __restrict__ Rkg,
                    const float* __restrict__ Rvg, float* __restrict__ Out) {
  __shared__ __align__(16) f16 Pf[QPB * PSTR];
  __shared__ __align__(16) f16 Tb[QPB * TSTR];   // bias table T, later reused as W
  __shared__ __align__(16) f16 Sb[64 * KSTR];    // shared staging (K/V/Rk/Rv chunks)
  __shared__ __align__(16) f16 Qb[QPB * KSTR];
  __shared__ float lsw[4][16];

  const int bid = blockIdx.x;
  const int b  = bid >> 10;
  const int h  = (bid >> 6) & 15;
  const int q0 = (bid & 63) * QPB;
  const int tid  = threadIdx.x;
  const int w    = tid >> 6;
  const int lane = tid & 63;
  const int quad = lane >> 4;
  const int l16  = lane & 15;

  auto stage64 = [&](const float* src, int rstride, f16* dst, int dstr) {
    #pragma unroll
    for (int jj = 0; jj < 4; ++jj) {
      int i = jj * 256 + tid;
      int r = i >> 4, c = (i & 15) << 2;
      float4 v = *(const float4*)(src + (size_t)r * rstride + c);
      f16x4 hv; hv.x = (f16)v.x; hv.y = (f16)v.y; hv.z = (f16)v.z; hv.w = (f16)v.w;
      *(f16x4*)(dst + r * dstr + c) = hv;
    }
  };

  // ---- stage Q tile (16x64, f16) ----
  {
    int r = tid >> 4, c = (tid & 15) << 2;
    float4 v = *(const float4*)(Qg + (size_t)(b * SS + q0 + r) * DD + h * HD + c);
    f16x4 hv; hv.x = (f16)v.x; hv.y = (f16)v.y; hv.z = (f16)v.z; hv.w = (f16)v.w;
    *(f16x4*)(Qb + r * KSTR + c) = hv;
  }
  __syncthreads();

  // Q fragments: serve as A (T-phase) and B (QK-phase) — identical register layout
  const f16x8 qf0 = *(const f16x8*)(Qb + l16 * KSTR + quad * 8);
  const f16x8 qf1 = *(const f16x8*)(Qb + l16 * KSTR + 32 + quad * 8);

  // ---- Phase T: bias table T[q][dist] = Q . Rk^T via MFMA (dists 0..511) ----
  #pragma unroll 1
  for (int cc = 0; cc < 8; ++cc) {
    stage64(Rkg + (size_t)(cc * 64) * HD, HD, Sb, KSTR);
    __syncthreads();
    f16x8 rk0 = *(const f16x8*)(Sb + (w * 16 + l16) * KSTR + quad * 8);
    f16x8 rk1 = *(const f16x8*)(Sb + (w * 16 + l16) * KSTR + 32 + quad * 8);
    f32x4 c = {0.f, 0.f, 0.f, 0.f};
    c = __builtin_amdgcn_mfma_f32_16x16x32_f16(qf0, rk0, c, 0, 0, 0);
    c = __builtin_amdgcn_mfma_f32_16x16x32_f16(qf1, rk1, c, 0, 0, 0);
    const int dbase = cc * 64 + w * 16 + l16;
    #pragma unroll
    for (int r = 0; r < 4; ++r)
      Tb[(quad * 4 + r) * TSTR + dbase] = (f16)c[r];
    __syncthreads();
  }
  // dist 512 by wave 0 (single column)
  if (w == 0) {
    float t = 0.f;
    #pragma unroll
    for (int i = 0; i < 16; ++i)
      t += (float)Qb[l16 * KSTR + quad * 16 + i] * Rkg[512 * HD + quad * 16 + i];
    t += __shfl_xor(t, 16);
    t += __shfl_xor(t, 32);
    if (quad == 0) Tb[l16 * TSTR + 512] = (f16)t;
  }

  // ---- Phase A: S^T = K . Q^T per 64-key chunk; exp -> Pf ----
  float psum = 0.f;
  #pragma unroll 1
  for (int kc = 0; kc < 16; ++kc) {
    stage64(Kg + (size_t)(b * SS + kc * 64) * DD + h * HD, DD, Sb, KSTR);
    __syncthreads();
    f16x8 ka0 = *(const f16x8*)(Sb + (w * 16 + l16) * KSTR + quad * 8);
    f16x8 ka1 = *(const f16x8*)(Sb + (w * 16 + l16) * KSTR + 32 + quad * 8);
    f32x4 c = {0.f, 0.f, 0.f, 0.f};
    c = __builtin_amdgcn_mfma_f32_16x16x32_f16(ka0, qf0, c, 0, 0, 0);
    c = __builtin_amdgcn_mfma_f32_16x16x32_f16(ka1, qf1, c, 0, 0, 0);
    // C: row = local key (quad*4+reg), col = q (l16) -> 4 consecutive keys per lane
    const int kb = kc * 64 + w * 16 + quad * 4;
    const int q  = q0 + l16;
    f16x4 pv;
    #pragma unroll
    for (int r = 0; r < 4; ++r) {
      int key = kb + r;
      int j = (q - key) & 1023;
      int dist = (j < 1024 - j) ? j : 1024 - j;
      float s = c[r] * 0.125f + (float)Tb[l16 * TSTR + dist];
      float p = __expf(s);            // no max-subtract: |s| <~ 8, fp32/f16-safe
      pv[r] = (f16)p;
      psum += p;
    }
    *(f16x4*)(Pf + l16 * PSTR + kb) = pv;  // packed b64, 2-way banks
    __syncthreads();
  }
  // row sums: lane's psum covers its (quad) keys of row l16; reduce across quads
  psum += __shfl_xor(psum, 16);
  psum += __shfl_xor(psum, 32);
  if (quad == 0) lsw[w][l16] = psum;

  // ---- Phase B: O = P . V via MFMA; wave w owns d-columns [w*16, w*16+16) ----
  f32x4 co = {0.f, 0.f, 0.f, 0.f};
  const int d = w * 16 + l16;
  #pragma unroll 1
  for (int kc = 0; kc < 16; ++kc) {
    stage64(Vg + (size_t)(b * SS + kc * 64) * DD + h * HD, DD, Sb, VSTR);
    __syncthreads();
    #pragma unroll
    for (int kd = 0; kd < 2; ++kd) {
      f16x8 bv;
      #pragma unroll
      for (int j = 0; j < 8; ++j)
        bv[j] = Sb[(kd * 32 + quad * 8 + j) * VSTR + d];
      f16x8 ap = *(const f16x8*)(Pf + l16 * PSTR + kc * 64 + kd * 32 + quad * 8);
      co = __builtin_amdgcn_mfma_f32_16x16x32_f16(ap, bv, co, 0, 0, 0);
    }
    __syncthreads();
  }

  // ---- Phase W: bucket weights W[q][dist] = Pf[q][q-dist] + Pf[q][q+dist] ----
  #pragma unroll 1
  for (int i = tid; i < QPB * 513; i += 256) {
    int ql = i / 513;
    int dist = i - ql * 513;
    int q = q0 + ql;
    int k1 = (q - dist) & 1023;
    float wv = (float)Pf[ql * PSTR + k1];
    if (dist != 0 && dist != 512) {
      int k2 = (q + dist) & 1023;
      wv += (float)Pf[ql * PSTR + k2];
    }
    Tb[ql * TSTR + dist] = (f16)wv;   // Tb reused as W
  }
  __syncthreads();

  // ---- Phase Wrelv: co += W . Rv (dists 0..511 via MFMA) ----
  #pragma unroll 1
  for (int cc = 0; cc < 8; ++cc) {
    stage64(Rvg + (size_t)(cc * 64) * HD, HD, Sb, VSTR);
    __syncthreads();
    #pragma unroll
    for (int kd = 0; kd < 2; ++kd) {
      f16x8 bv;
      #pragma unroll
      for (int j = 0; j < 8; ++j)
        bv[j] = Sb[(kd * 32 + quad * 8 + j) * VSTR + d];
      f16x8 aw = *(const f16x8*)(Tb + l16 * TSTR + cc * 64 + kd * 32 + quad * 8);
      co = __builtin_amdgcn_mfma_f32_16x16x32_f16(aw, bv, co, 0, 0, 0);
    }
    __syncthreads();
  }

  // ---- finalize: dist-512 rel_v term + normalize + store ----
  const float rv512 = Rvg[512 * HD + d];
  #pragma unroll
  for (int r = 0; r < 4; ++r) {
    int ql = quad * 4 + r;
    float l = lsw[0][ql] + lsw[1][ql] + lsw[2][ql] + lsw[3][ql];
    float o = co[r] + (float)Tb[ql * TSTR + 512] * rv512;
    Out[(size_t)(b * SS + q0 + ql) * DD + h * HD + d] = o / l;
  }
}

extern "C" void kernel_launch(void* const* d_in, const int* in_sizes, int n_in,
                              void* d_out, int out_size, void* d_ws, size_t ws_size,
                              hipStream_t stream) {
  const float* q  = (const float*)d_in[0];
  const float* k  = (const float*)d_in[1];
  const float* v  = (const float*)d_in[2];
  const float* rk = (const float*)d_in[3];
  const float* rv = (const float*)d_in[4];
  float* out = (float*)d_out;
  const int nblocks = BB * HH * (SS / QPB);  // 8192
  circ_attn_mfma<<<dim3(nblocks), dim3(256), 0, stream>>>(q, k, v, rk, rv, out);
}

// Round 3
// 669.780 us; speedup vs baseline: 6.0845x; 1.1993x over previous
//
#include <hip/hip_runtime.h>

typedef _Float16 f16;
typedef __attribute__((ext_vector_type(4))) _Float16 f16x4;
typedef __attribute__((ext_vector_type(8))) _Float16 f16x8;
typedef __attribute__((ext_vector_type(4))) float f32x4;

#define BB 8
#define SS 1024
#define DD 1024
#define HH 16
#define HD 64
#define QPB 16
#define PSTR 1032   // P row stride (f16): 2064 B, 16B-aligned
#define TSTR 520    // T/W row stride (f16): 1040 B, 16B-aligned
#define KSTR 72     // staging stride: 144 B rows, b128 ops near-uniform banks
#define RVSTR 520   // Rvt global row stride (f16), 16B-aligned rows

#define VT_ELEMS ((size_t)BB * HH * HD * SS)          // 8,388,608 f16
#define RVT_ELEMS ((size_t)HD * RVSTR)                // 33,280 f16
#define WS_NEED ((VT_ELEMS + RVT_ELEMS) * sizeof(f16))

__device__ inline f16x8 cvt16(float4 a, float4 b) {
  f16x8 h;
  h[0] = (f16)a.x; h[1] = (f16)a.y; h[2] = (f16)a.z; h[3] = (f16)a.w;
  h[4] = (f16)b.x; h[5] = (f16)b.y; h[6] = (f16)b.z; h[7] = (f16)b.w;
  return h;
}

// ---- prep: V -> Vt[b][h][d][s] (f16), Rv[0:512] -> Rvt[d][dist] (f16) ----
__global__ __launch_bounds__(256, 2)
void prep_kernel(const float* __restrict__ Vg, const float* __restrict__ Rvg,
                 f16* __restrict__ Vt, f16* __restrict__ Rvt) {
  __shared__ __align__(16) f16 Tt[64 * KSTR];
  const int tid = threadIdx.x;
  const int sr = tid >> 2, cs = (tid & 3) * 16;
  const int bid = blockIdx.x;

  const float* src;
  int srcstride;
  f16* dst;
  int dststride, dstcol;
  if (bid < 2048) {
    int b = bid >> 8, h = (bid >> 4) & 15, tc = bid & 15;
    src = Vg + ((size_t)(b * SS + tc * 64)) * DD + h * HD;
    srcstride = DD;
    dst = Vt + ((size_t)((b * HH + h) * HD)) * SS;
    dststride = SS; dstcol = tc * 64;
  } else {
    int cc = bid - 2048;                       // 0..7, dists 0..511
    src = Rvg + ((size_t)(cc * 64)) * HD;
    srcstride = HD;
    dst = Rvt;
    dststride = RVSTR; dstcol = cc * 64;
  }
  // load 64x64 fp32 tile (rows = key/dist, cols = d), cvt f16 -> LDS
  {
    const float* s = src + (size_t)sr * srcstride + cs;
    float4 v0 = *(const float4*)(s);
    float4 v1 = *(const float4*)(s + 4);
    float4 v2 = *(const float4*)(s + 8);
    float4 v3 = *(const float4*)(s + 12);
    *(f16x8*)(Tt + sr * KSTR + cs) = cvt16(v0, v1);
    *(f16x8*)(Tt + sr * KSTR + cs + 8) = cvt16(v2, v3);
  }
  __syncthreads();
  // write transposed: row d = sr, cols = 16 keys/dists starting at cs
  {
    f16x8 o0, o1;
    #pragma unroll
    for (int i = 0; i < 8; ++i) o0[i] = Tt[(cs + i) * KSTR + sr];
    #pragma unroll
    for (int i = 0; i < 8; ++i) o1[i] = Tt[(cs + 8 + i) * KSTR + sr];
    f16* o = dst + (size_t)sr * dststride + dstcol + cs;
    *(f16x8*)(o) = o0;
    *(f16x8*)(o + 8) = o1;
  }
}

// ---- main kernel: LDS = Pf 33024 + Tb 16640 + Sb 9216 + lsw 256 = 59136 B ----
__global__ __launch_bounds__(256, 2)
void circ_attn_v3(const float* __restrict__ Qg, const float* __restrict__ Kg,
                  const float* __restrict__ Rkg, const float* __restrict__ Rvg,
                  const f16* __restrict__ Vt, const f16* __restrict__ Rvt,
                  float* __restrict__ Out) {
  __shared__ __align__(16) f16 Pf[QPB * PSTR];
  __shared__ __align__(16) f16 Tb[QPB * TSTR];   // bias table T, later reused as W
  __shared__ __align__(16) f16 Sb[64 * KSTR];    // shared staging buffer
  __shared__ float lsw[4][16];

  const int bid = blockIdx.x;
  const int b = bid >> 10;
  const int h = (bid >> 6) & 15;
  const int q0 = (bid & 63) * QPB;
  const int tid = threadIdx.x;
  const int w = tid >> 6;
  const int lane = tid & 63;
  const int quad = lane >> 4;
  const int l16 = lane & 15;
  const int sr = tid >> 2, cs = (tid & 3) * 16;  // staging row / col-segment

  // ---- Q fragments straight from global (A-layout == B-layout) ----
  f16x8 qf0, qf1;
  {
    const float* qrow = Qg + ((size_t)(b * SS + q0 + l16)) * DD + h * HD;
    float4 a0 = *(const float4*)(qrow + quad * 8);
    float4 a1 = *(const float4*)(qrow + quad * 8 + 4);
    float4 a2 = *(const float4*)(qrow + 32 + quad * 8);
    float4 a3 = *(const float4*)(qrow + 32 + quad * 8 + 4);
    qf0 = cvt16(a0, a1);
    qf1 = cvt16(a2, a3);
  }

  // ---- Phase T: T[q][dist] = Q . Rk^T (dists 0..511) ----
  #pragma unroll 1
  for (int cc = 0; cc < 8; ++cc) {
    {
      const float* s = Rkg + ((size_t)(cc * 64 + sr)) * HD + cs;
      float4 v0 = *(const float4*)(s);
      float4 v1 = *(const float4*)(s + 4);
      float4 v2 = *(const float4*)(s + 8);
      float4 v3 = *(const float4*)(s + 12);
      *(f16x8*)(Sb + sr * KSTR + cs) = cvt16(v0, v1);
      *(f16x8*)(Sb + sr * KSTR + cs + 8) = cvt16(v2, v3);
    }
    __syncthreads();
    f16x8 rk0 = *(const f16x8*)(Sb + (w * 16 + l16) * KSTR + quad * 8);
    f16x8 rk1 = *(const f16x8*)(Sb + (w * 16 + l16) * KSTR + 32 + quad * 8);
    f32x4 c = {0.f, 0.f, 0.f, 0.f};
    c = __builtin_amdgcn_mfma_f32_16x16x32_f16(qf0, rk0, c, 0, 0, 0);
    c = __builtin_amdgcn_mfma_f32_16x16x32_f16(qf1, rk1, c, 0, 0, 0);
    const int dbase = cc * 64 + w * 16 + l16;
    #pragma unroll
    for (int r = 0; r < 4; ++r)
      Tb[(quad * 4 + r) * TSTR + dbase] = (f16)c[r];
    __syncthreads();
  }
  // dist 512 (wave 0 only)
  if (w == 0) {
    const float* rk = Rkg + 512 * HD;
    float t = 0.f;
    #pragma unroll
    for (int j = 0; j < 8; ++j) t += (float)qf0[j] * rk[quad * 8 + j];
    #pragma unroll
    for (int j = 0; j < 8; ++j) t += (float)qf1[j] * rk[32 + quad * 8 + j];
    t += __shfl_xor(t, 16);
    t += __shfl_xor(t, 32);
    if (quad == 0) Tb[l16 * TSTR + 512] = (f16)t;
  }

  // ---- Phase A: S^T = K . Q^T per 64-key chunk; exp -> Pf ----
  const float* kbase = Kg + (size_t)b * SS * DD + h * HD;
  float4 p0, p1, p2, p3;
  {
    const float* s = kbase + (size_t)sr * DD + cs;
    p0 = *(const float4*)(s);     p1 = *(const float4*)(s + 4);
    p2 = *(const float4*)(s + 8); p3 = *(const float4*)(s + 12);
  }
  float psum = 0.f;
  #pragma unroll 1
  for (int kc = 0; kc < 16; ++kc) {
    __syncthreads();                      // Sb free
    *(f16x8*)(Sb + sr * KSTR + cs) = cvt16(p0, p1);
    *(f16x8*)(Sb + sr * KSTR + cs + 8) = cvt16(p2, p3);
    __syncthreads();                      // Sb ready
    if (kc < 15) {                        // prefetch next tile (overlaps consume)
      const float* s = kbase + ((size_t)((kc + 1) * 64 + sr)) * DD + cs;
      p0 = *(const float4*)(s);     p1 = *(const float4*)(s + 4);
      p2 = *(const float4*)(s + 8); p3 = *(const float4*)(s + 12);
    }
    f16x8 ka0 = *(const f16x8*)(Sb + (w * 16 + l16) * KSTR + quad * 8);
    f16x8 ka1 = *(const f16x8*)(Sb + (w * 16 + l16) * KSTR + 32 + quad * 8);
    f32x4 c = {0.f, 0.f, 0.f, 0.f};
    c = __builtin_amdgcn_mfma_f32_16x16x32_f16(ka0, qf0, c, 0, 0, 0);
    c = __builtin_amdgcn_mfma_f32_16x16x32_f16(ka1, qf1, c, 0, 0, 0);
    const int kb = kc * 64 + w * 16 + quad * 4;
    const int q = q0 + l16;
    f16x4 pv;
    #pragma unroll
    for (int r = 0; r < 4; ++r) {
      int key = kb + r;
      int j = (q - key) & 1023;
      int dist = (j < 1024 - j) ? j : 1024 - j;
      float sc_ = c[r] * 0.125f + (float)Tb[l16 * TSTR + dist];
      float p = __expf(sc_);              // no max-subtract: |s| small, fp32-safe
      pv[r] = (f16)p;
      psum += p;
    }
    *(f16x4*)(Pf + l16 * PSTR + kb) = pv;
  }
  psum += __shfl_xor(psum, 16);
  psum += __shfl_xor(psum, 32);
  if (quad == 0) lsw[w][l16] = psum;

  // ---- Phase B: O = P . V ; wave w owns d-columns [w*16, w*16+16) ----
  const f16* vt = Vt + ((size_t)((b * HH + h) * HD)) * SS;  // rows d, stride SS
  f16x8 v0 = *(const f16x8*)(vt + (size_t)sr * SS + cs);
  f16x8 v1 = *(const f16x8*)(vt + (size_t)sr * SS + cs + 8);
  f32x4 co = {0.f, 0.f, 0.f, 0.f};
  #pragma unroll 1
  for (int kc = 0; kc < 16; ++kc) {
    __syncthreads();                      // Sb free
    *(f16x8*)(Sb + sr * KSTR + cs) = v0;
    *(f16x8*)(Sb + sr * KSTR + cs + 8) = v1;
    __syncthreads();                      // Sb ready
    if (kc < 15) {
      const f16* s = vt + (size_t)sr * SS + (kc + 1) * 64 + cs;
      v0 = *(const f16x8*)(s);
      v1 = *(const f16x8*)(s + 8);
    }
    #pragma unroll
    for (int kd = 0; kd < 2; ++kd) {
      f16x8 ap = *(const f16x8*)(Pf + l16 * PSTR + kc * 64 + kd * 32 + quad * 8);
      f16x8 bv = *(const f16x8*)(Sb + (w * 16 + l16) * KSTR + kd * 32 + quad * 8);
      co = __builtin_amdgcn_mfma_f32_16x16x32_f16(ap, bv, co, 0, 0, 0);
    }
  }

  // ---- Phase W: W[q][dist] = Pf[q][(q-dist)&1023] (+ Pf[q][(q+dist)&1023]) ----
  #pragma unroll 1
  for (int i = tid; i < QPB * 513; i += 256) {
    int ql = i / 513;
    int dist = i - ql * 513;
    int q = q0 + ql;
    int k1 = (q - dist) & 1023;
    float wv = (float)Pf[ql * PSTR + k1];
    if (dist != 0 && dist != 512) {
      int k2 = (q + dist) & 1023;
      wv += (float)Pf[ql * PSTR + k2];
    }
    Tb[ql * TSTR + dist] = (f16)wv;       // Tb reused as W
  }

  // ---- Phase Wrelv: co += W . Rv (dists 0..511) ----
  f16x8 r0 = *(const f16x8*)(Rvt + (size_t)sr * RVSTR + cs);
  f16x8 r1 = *(const f16x8*)(Rvt + (size_t)sr * RVSTR + cs + 8);
  #pragma unroll 1
  for (int cc = 0; cc < 8; ++cc) {
    __syncthreads();                      // Sb free (also orders Phase-W writes)
    *(f16x8*)(Sb + sr * KSTR + cs) = r0;
    *(f16x8*)(Sb + sr * KSTR + cs + 8) = r1;
    __syncthreads();                      // Sb ready
    if (cc < 7) {
      const f16* s = Rvt + (size_t)sr * RVSTR + (cc + 1) * 64 + cs;
      r0 = *(const f16x8*)(s);
      r1 = *(const f16x8*)(s + 8);
    }
    #pragma unroll
    for (int kd = 0; kd < 2; ++kd) {
      f16x8 aw = *(const f16x8*)(Tb + l16 * TSTR + cc * 64 + kd * 32 + quad * 8);
      f16x8 bv = *(const f16x8*)(Sb + (w * 16 + l16) * KSTR + kd * 32 + quad * 8);
      co = __builtin_amdgcn_mfma_f32_16x16x32_f16(aw, bv, co, 0, 0, 0);
    }
  }

  // ---- finalize: dist-512 rel_v term + normalize + store ----
  const int d = w * 16 + l16;
  const float rv512 = Rvg[512 * HD + d];
  #pragma unroll
  for (int r = 0; r < 4; ++r) {
    int ql = quad * 4 + r;
    float l = lsw[0][ql] + lsw[1][ql] + lsw[2][ql] + lsw[3][ql];
    float o = co[r] + (float)Tb[ql * TSTR + 512] * rv512;
    Out[((size_t)(b * SS + q0 + ql)) * DD + h * HD + d] = o / l;
  }
}

// ---- fallback (R2 kernel, used only if ws_size is too small) ----
#define FPSTR 1032
#define FVSTR 68
__global__ __launch_bounds__(256, 2)
void circ_attn_mfma(const float* __restrict__ Qg, const float* __restrict__ Kg,
                    const float* __restrict__ Vg, const float* __restrict__ Rkg,
                    const float* __restrict__ Rvg, float* __restrict__ Out) {
  __shared__ __align__(16) f16 Pf[QPB * FPSTR];
  __shared__ __align__(16) f16 Tb[QPB * TSTR];
  __shared__ __align__(16) f16 Sb[64 * KSTR];
  __shared__ __align__(16) f16 Qb[QPB * KSTR];
  __shared__ float lsw[4][16];
  const int bid = blockIdx.x;
  const int b = bid >> 10, h = (bid >> 6) & 15, q0 = (bid & 63) * QPB;
  const int tid = threadIdx.x, w = tid >> 6, lane = tid & 63;
  const int quad = lane >> 4, l16 = lane & 15;
  auto stage64 = [&](const float* src, int rstride, f16* dst, int dstr) {
    #pragma unroll
    for (int jj = 0; jj < 4; ++jj) {
      int i = jj * 256 + tid;
      int r = i >> 4, c = (i & 15) << 2;
      float4 v = *(const float4*)(src + (size_t)r * rstride + c);
      f16x4 hv; hv[0] = (f16)v.x; hv[1] = (f16)v.y; hv[2] = (f16)v.z; hv[3] = (f16)v.w;
      *(f16x4*)(dst + r * dstr + c) = hv;
    }
  };
  {
    int r = tid >> 4, c = (tid & 15) << 2;
    float4 v = *(const float4*)(Qg + (size_t)(b * SS + q0 + r) * DD + h * HD + c);
    f16x4 hv; hv[0] = (f16)v.x; hv[1] = (f16)v.y; hv[2] = (f16)v.z; hv[3] = (f16)v.w;
    *(f16x4*)(Qb + r * KSTR + c) = hv;
  }
  __syncthreads();
  const f16x8 qf0 = *(const f16x8*)(Qb + l16 * KSTR + quad * 8);
  const f16x8 qf1 = *(const f16x8*)(Qb + l16 * KSTR + 32 + quad * 8);
  #pragma unroll 1
  for (int cc = 0; cc < 8; ++cc) {
    stage64(Rkg + (size_t)(cc * 64) * HD, HD, Sb, KSTR);
    __syncthreads();
    f16x8 rk0 = *(const f16x8*)(Sb + (w * 16 + l16) * KSTR + quad * 8);
    f16x8 rk1 = *(const f16x8*)(Sb + (w * 16 + l16) * KSTR + 32 + quad * 8);
    f32x4 c = {0.f, 0.f, 0.f, 0.f};
    c = __builtin_amdgcn_mfma_f32_16x16x32_f16(qf0, rk0, c, 0, 0, 0);
    c = __builtin_amdgcn_mfma_f32_16x16x32_f16(qf1, rk1, c, 0, 0, 0);
    const int dbase = cc * 64 + w * 16 + l16;
    #pragma unroll
    for (int r = 0; r < 4; ++r) Tb[(quad * 4 + r) * TSTR + dbase] = (f16)c[r];
    __syncthreads();
  }
  if (w == 0) {
    float t = 0.f;
    #pragma unroll
    for (int i = 0; i < 16; ++i)
      t += (float)Qb[l16 * KSTR + quad * 16 + i] * Rkg[512 * HD + quad * 16 + i];
    t += __shfl_xor(t, 16); t += __shfl_xor(t, 32);
    if (quad == 0) Tb[l16 * TSTR + 512] = (f16)t;
  }
  float psum = 0.f;
  #pragma unroll 1
  for (int kc = 0; kc < 16; ++kc) {
    stage64(Kg + (size_t)(b * SS + kc * 64) * DD + h * HD, DD, Sb, KSTR);
    __syncthreads();
    f16x8 ka0 = *(const f16x8*)(Sb + (w * 16 + l16) * KSTR + quad * 8);
    f16x8 ka1 = *(const f16x8*)(Sb + (w * 16 + l16) * KSTR + 32 + quad * 8);
    f32x4 c = {0.f, 0.f, 0.f, 0.f};
    c = __builtin_amdgcn_mfma_f32_16x16x32_f16(ka0, qf0, c, 0, 0, 0);
    c = __builtin_amdgcn_mfma_f32_16x16x32_f16(ka1, qf1, c, 0, 0, 0);
    const int kb = kc * 64 + w * 16 + quad * 4;
    const int q = q0 + l16;
    f16x4 pv;
    #pragma unroll
    for (int r = 0; r < 4; ++r) {
      int key = kb + r;
      int j = (q - key) & 1023;
      int dist = (j < 1024 - j) ? j : 1024 - j;
      float s = c[r] * 0.125f + (float)Tb[l16 * TSTR + dist];
      float p = __expf(s);
      pv[r] = (f16)p;
      psum += p;
    }
    *(f16x4*)(Pf + l16 * FPSTR + kb) = pv;
    __syncthreads();
  }
  psum += __shfl_xor(psum, 16); psum += __shfl_xor(psum, 32);
  if (quad == 0) lsw[w][l16] = psum;
  f32x4 co = {0.f, 0.f, 0.f, 0.f};
  const int d = w * 16 + l16;
  #pragma unroll 1
  for (int kc = 0; kc < 16; ++kc) {
    stage64(Vg + (size_t)(b * SS + kc * 64) * DD + h * HD, DD, Sb, FVSTR);
    __syncthreads();
    #pragma unroll
    for (int kd = 0; kd < 2; ++kd) {
      f16x8 bv;
      #pragma unroll
      for (int j = 0; j < 8; ++j) bv[j] = Sb[(kd * 32 + quad * 8 + j) * FVSTR + d];
      f16x8 ap = *(const f16x8*)(Pf + l16 * FPSTR + kc * 64 + kd * 32 + quad * 8);
      co = __builtin_amdgcn_mfma_f32_16x16x32_f16(ap, bv, co, 0, 0, 0);
    }
    __syncthreads();
  }
  #pragma unroll 1
  for (int i = tid; i < QPB * 513; i += 256) {
    int ql = i / 513, dist = i - ql * 513, q = q0 + ql;
    int k1 = (q - dist) & 1023;
    float wv = (float)Pf[ql * FPSTR + k1];
    if (dist != 0 && dist != 512) wv += (float)Pf[ql * FPSTR + ((q + dist) & 1023)];
    Tb[ql * TSTR + dist] = (f16)wv;
  }
  __syncthreads();
  #pragma unroll 1
  for (int cc = 0; cc < 8; ++cc) {
    stage64(Rvg + (size_t)(cc * 64) * HD, HD, Sb, FVSTR);
    __syncthreads();
    #pragma unroll
    for (int kd = 0; kd < 2; ++kd) {
      f16x8 bv;
      #pragma unroll
      for (int j = 0; j < 8; ++j) bv[j] = Sb[(kd * 32 + quad * 8 + j) * FVSTR + d];
      f16x8 aw = *(const f16x8*)(Tb + l16 * TSTR + cc * 64 + kd * 32 + quad * 8);
      co = __builtin_amdgcn_mfma_f32_16x16x32_f16(aw, bv, co, 0, 0, 0);
    }
    __syncthreads();
  }
  const float rv512 = Rvg[512 * HD + d];
  #pragma unroll
  for (int r = 0; r < 4; ++r) {
    int ql = quad * 4 + r;
    float l = lsw[0][ql] + lsw[1][ql] + lsw[2][ql] + lsw[3][ql];
    float o = co[r] + (float)Tb[ql * TSTR + 512] * rv512;
    Out[(size_t)(b * SS + q0 + ql) * DD + h * HD + d] = o / l;
  }
}

extern "C" void kernel_launch(void* const* d_in, const int* in_sizes, int n_in,
                              void* d_out, int out_size, void* d_ws, size_t ws_size,
                              hipStream_t stream) {
  const float* q  = (const float*)d_in[0];
  const float* k  = (const float*)d_in[1];
  const float* v  = (const float*)d_in[2];
  const float* rk = (const float*)d_in[3];
  const float* rv = (const float*)d_in[4];
  float* out = (float*)d_out;
  const int nblocks = BB * HH * (SS / QPB);  // 8192
  if (ws_size >= WS_NEED) {
    f16* vt  = (f16*)d_ws;
    f16* rvt = vt + VT_ELEMS;
    prep_kernel<<<dim3(2048 + 8), dim3(256), 0, stream>>>(v, rv, vt, rvt);
    circ_attn_v3<<<dim3(nblocks), dim3(256), 0, stream>>>(q, k, rk, rv, vt, rvt, out);
  } else {
    circ_attn_mfma<<<dim3(nblocks), dim3(256), 0, stream>>>(q, k, v, rk, rv, out);
  }
}

// Round 4
// 625.386 us; speedup vs baseline: 6.5164x; 1.0710x over previous
//
#include <hip/hip_runtime.h>

typedef _Float16 f16;
typedef __attribute__((ext_vector_type(4))) _Float16 f16x4;
typedef __attribute__((ext_vector_type(8))) _Float16 f16x8;
typedef __attribute__((ext_vector_type(4))) float f32x4;

#define BB 8
#define SS 1024
#define DD 1024
#define HH 16
#define HD 64
#define QPB 16
#define PROW 1024   // Pf row length (f16); rows bank-aligned, XOR swizzle on 8-elem granules
#define TSTR 520    // T/W row stride (f16): 1040 B, 16B-aligned
#define KSTR 72     // prep-kernel LDS staging stride
#define RVSTR 520   // Rvt global row stride (f16), 16B-aligned rows

#define VT_ELEMS ((size_t)BB * HH * HD * SS)          // 8,388,608 f16
#define RVT_ELEMS ((size_t)HD * RVSTR)                // 33,280 f16
#define WS_NEED ((VT_ELEMS + RVT_ELEMS) * sizeof(f16))

__device__ inline f16x8 cvt16(float4 a, float4 b) {
  f16x8 h;
  h[0] = (f16)a.x; h[1] = (f16)a.y; h[2] = (f16)a.z; h[3] = (f16)a.w;
  h[4] = (f16)b.x; h[5] = (f16)b.y; h[6] = (f16)b.z; h[7] = (f16)b.w;
  return h;
}

// Pf bank swizzle: XOR 8-elem (16 B) granule index with (row & 7)
__device__ inline int swz(int row, int col) {
  return (((col >> 3) ^ (row & 7)) << 3) | (col & 7);
}

// ---- prep: V -> Vt[b][h][d][s] (f16), Rv[0:512] -> Rvt[d][dist] (f16) ----
__global__ __launch_bounds__(256, 2)
void prep_kernel(const float* __restrict__ Vg, const float* __restrict__ Rvg,
                 f16* __restrict__ Vt, f16* __restrict__ Rvt) {
  __shared__ __align__(16) f16 Tt[64 * KSTR];
  const int tid = threadIdx.x;
  const int sr = tid >> 2, cs = (tid & 3) * 16;
  const int bid = blockIdx.x;

  const float* src;
  int srcstride;
  f16* dst;
  int dststride, dstcol;
  if (bid < 2048) {
    int b = bid >> 8, h = (bid >> 4) & 15, tc = bid & 15;
    src = Vg + ((size_t)(b * SS + tc * 64)) * DD + h * HD;
    srcstride = DD;
    dst = Vt + ((size_t)((b * HH + h) * HD)) * SS;
    dststride = SS; dstcol = tc * 64;
  } else {
    int cc = bid - 2048;                       // 0..7, dists 0..511
    src = Rvg + ((size_t)(cc * 64)) * HD;
    srcstride = HD;
    dst = Rvt;
    dststride = RVSTR; dstcol = cc * 64;
  }
  {
    const float* s = src + (size_t)sr * srcstride + cs;
    float4 v0 = *(const float4*)(s);
    float4 v1 = *(const float4*)(s + 4);
    float4 v2 = *(const float4*)(s + 8);
    float4 v3 = *(const float4*)(s + 12);
    *(f16x8*)(Tt + sr * KSTR + cs) = cvt16(v0, v1);
    *(f16x8*)(Tt + sr * KSTR + cs + 8) = cvt16(v2, v3);
  }
  __syncthreads();
  {
    f16x8 o0, o1;
    #pragma unroll
    for (int i = 0; i < 8; ++i) o0[i] = Tt[(cs + i) * KSTR + sr];
    #pragma unroll
    for (int i = 0; i < 8; ++i) o1[i] = Tt[(cs + 8 + i) * KSTR + sr];
    f16* o = dst + (size_t)sr * dststride + dstcol + cs;
    *(f16x8*)(o) = o0;
    *(f16x8*)(o + 8) = o1;
  }
}

// ---- main kernel v4: LDS = Pf 32768 + Tb 16640 + lsw 256 = 49664 B -> 3 blocks/CU,
// no LDS staging of K/Rk/V/Rv (per-wave-private fragments straight from global),
// 3 barriers total (was 96).
__global__ __launch_bounds__(256, 3)
void circ_attn_v4(const float* __restrict__ Qg, const float* __restrict__ Kg,
                  const float* __restrict__ Rkg, const float* __restrict__ Rvg,
                  const f16* __restrict__ Vt, const f16* __restrict__ Rvt,
                  float* __restrict__ Out) {
  __shared__ __align__(16) f16 Pf[QPB * PROW];
  __shared__ __align__(16) f16 Tb[QPB * TSTR];   // bias table T, later reused as W
  __shared__ float lsw[4][16];

  const int bid = blockIdx.x;
  const int b = bid >> 10;
  const int h = (bid >> 6) & 15;
  const int q0 = (bid & 63) * QPB;
  const int tid = threadIdx.x;
  const int w = tid >> 6;
  const int lane = tid & 63;
  const int quad = lane >> 4;
  const int l16 = lane & 15;

  // ---- Q fragments straight from global (A-layout == B-layout) ----
  f16x8 qf0, qf1;
  {
    const float* qrow = Qg + ((size_t)(b * SS + q0 + l16)) * DD + h * HD;
    float4 a0 = *(const float4*)(qrow + quad * 8);
    float4 a1 = *(const float4*)(qrow + quad * 8 + 4);
    float4 a2 = *(const float4*)(qrow + 32 + quad * 8);
    float4 a3 = *(const float4*)(qrow + 32 + quad * 8 + 4);
    qf0 = cvt16(a0, a1);
    qf1 = cvt16(a2, a3);
  }

  // ---- Phase T: T[q][dist] = Q . Rk^T (dists 0..511), B-frags from global ----
  {
    const float* rkp = Rkg + ((size_t)(w * 16 + l16)) * HD + quad * 8;
    #pragma unroll 1
    for (int cc = 0; cc < 8; ++cc) {
      const float* s = rkp + (size_t)cc * 64 * HD;
      float4 a0 = *(const float4*)(s);
      float4 a1 = *(const float4*)(s + 4);
      float4 a2 = *(const float4*)(s + 32);
      float4 a3 = *(const float4*)(s + 36);
      f16x8 rk0 = cvt16(a0, a1);
      f16x8 rk1 = cvt16(a2, a3);
      f32x4 c = {0.f, 0.f, 0.f, 0.f};
      c = __builtin_amdgcn_mfma_f32_16x16x32_f16(qf0, rk0, c, 0, 0, 0);
      c = __builtin_amdgcn_mfma_f32_16x16x32_f16(qf1, rk1, c, 0, 0, 0);
      const int dbase = cc * 64 + w * 16 + l16;
      #pragma unroll
      for (int r = 0; r < 4; ++r)
        Tb[(quad * 4 + r) * TSTR + dbase] = (f16)c[r];
    }
  }
  // dist 512 (wave 0 only)
  if (w == 0) {
    const float* rk = Rkg + 512 * HD;
    float t = 0.f;
    #pragma unroll
    for (int j = 0; j < 8; ++j) t += (float)qf0[j] * rk[quad * 8 + j];
    #pragma unroll
    for (int j = 0; j < 8; ++j) t += (float)qf1[j] * rk[32 + quad * 8 + j];
    t += __shfl_xor(t, 16);
    t += __shfl_xor(t, 32);
    if (quad == 0) Tb[l16 * TSTR + 512] = (f16)t;
  }
  __syncthreads();   // barrier 1: Tb(T) ready

  // ---- Phase A: S^T = K . Q^T ; A-frags from global, exp -> Pf (swizzled) ----
  {
    const float* kp = Kg + ((size_t)(b * SS + w * 16 + l16)) * DD + h * HD + quad * 8;
    float4 k0 = *(const float4*)(kp);
    float4 k1 = *(const float4*)(kp + 4);
    float4 k2 = *(const float4*)(kp + 32);
    float4 k3 = *(const float4*)(kp + 36);
    float psum = 0.f;
    #pragma unroll 1
    for (int kc = 0; kc < 16; ++kc) {
      f16x8 ka0 = cvt16(k0, k1);
      f16x8 ka1 = cvt16(k2, k3);
      if (kc < 15) {                        // prefetch next chunk
        const float* s = kp + (size_t)(kc + 1) * 64 * DD;
        k0 = *(const float4*)(s);
        k1 = *(const float4*)(s + 4);
        k2 = *(const float4*)(s + 32);
        k3 = *(const float4*)(s + 36);
      }
      f32x4 c = {0.f, 0.f, 0.f, 0.f};
      c = __builtin_amdgcn_mfma_f32_16x16x32_f16(ka0, qf0, c, 0, 0, 0);
      c = __builtin_amdgcn_mfma_f32_16x16x32_f16(ka1, qf1, c, 0, 0, 0);
      const int kb = kc * 64 + w * 16 + quad * 4;
      const int q = q0 + l16;
      f16x4 pv;
      #pragma unroll
      for (int r = 0; r < 4; ++r) {
        int key = kb + r;
        int j = (q - key) & 1023;
        int dist = (j < 1024 - j) ? j : 1024 - j;
        float sc_ = c[r] * 0.125f + (float)Tb[l16 * TSTR + dist];
        float p = __expf(sc_);              // no max-subtract: |s| small, fp32-safe
        pv[r] = (f16)p;
        psum += p;
      }
      *(f16x4*)(Pf + l16 * PROW + swz(l16, kb)) = pv;   // kb..kb+3 same granule
    }
    psum += __shfl_xor(psum, 16);
    psum += __shfl_xor(psum, 32);
    if (quad == 0) lsw[w][l16] = psum;
  }
  __syncthreads();   // barrier 2: Pf + lsw ready

  // ---- Phase B: O = P . V ; B-frags from Vt (f16 global), A-frags from Pf ----
  f32x4 co = {0.f, 0.f, 0.f, 0.f};
  {
    const f16* vtp = Vt + ((size_t)((b * HH + h) * HD + w * 16 + l16)) * SS + quad * 8;
    f16x8 v0 = *(const f16x8*)(vtp);
    f16x8 v1 = *(const f16x8*)(vtp + 32);
    #pragma unroll 1
    for (int kc = 0; kc < 16; ++kc) {
      f16x8 cb0 = v0, cb1 = v1;
      if (kc < 15) {
        const f16* s = vtp + (kc + 1) * 64;
        v0 = *(const f16x8*)(s);
        v1 = *(const f16x8*)(s + 32);
      }
      f16x8 ap0 = *(const f16x8*)(Pf + l16 * PROW + swz(l16, kc * 64 + quad * 8));
      f16x8 ap1 = *(const f16x8*)(Pf + l16 * PROW + swz(l16, kc * 64 + 32 + quad * 8));
      co = __builtin_amdgcn_mfma_f32_16x16x32_f16(ap0, cb0, co, 0, 0, 0);
      co = __builtin_amdgcn_mfma_f32_16x16x32_f16(ap1, cb1, co, 0, 0, 0);
    }
  }

  // ---- Phase W: W[q][dist] = Pf[q][(q-dist)&1023] (+ Pf[q][(q+dist)&1023]) ----
  #pragma unroll 1
  for (int i = tid; i < QPB * 513; i += 256) {
    int ql = i / 513;
    int dist = i - ql * 513;
    int q = q0 + ql;
    int k1 = (q - dist) & 1023;
    float wv = (float)Pf[ql * PROW + swz(ql, k1)];
    if (dist != 0 && dist != 512) {
      int k2 = (q + dist) & 1023;
      wv += (float)Pf[ql * PROW + swz(ql, k2)];
    }
    Tb[ql * TSTR + dist] = (f16)wv;       // Tb reused as W
  }
  __syncthreads();   // barrier 3: W ready

  // ---- Phase Wrelv: co += W . Rv (dists 0..511), B-frags from Rvt ----
  {
    const f16* rvp = Rvt + ((size_t)(w * 16 + l16)) * RVSTR + quad * 8;
    f16x8 r0 = *(const f16x8*)(rvp);
    f16x8 r1 = *(const f16x8*)(rvp + 32);
    #pragma unroll 1
    for (int cc = 0; cc < 8; ++cc) {
      f16x8 cb0 = r0, cb1 = r1;
      if (cc < 7) {
        const f16* s = rvp + (cc + 1) * 64;
        r0 = *(const f16x8*)(s);
        r1 = *(const f16x8*)(s + 32);
      }
      f16x8 aw0 = *(const f16x8*)(Tb + l16 * TSTR + cc * 64 + quad * 8);
      f16x8 aw1 = *(const f16x8*)(Tb + l16 * TSTR + cc * 64 + 32 + quad * 8);
      co = __builtin_amdgcn_mfma_f32_16x16x32_f16(aw0, cb0, co, 0, 0, 0);
      co = __builtin_amdgcn_mfma_f32_16x16x32_f16(aw1, cb1, co, 0, 0, 0);
    }
  }

  // ---- finalize: dist-512 rel_v term + normalize + store ----
  const int d = w * 16 + l16;
  const float rv512 = Rvg[512 * HD + d];
  #pragma unroll
  for (int r = 0; r < 4; ++r) {
    int ql = quad * 4 + r;
    float l = lsw[0][ql] + lsw[1][ql] + lsw[2][ql] + lsw[3][ql];
    float o = co[r] + (float)Tb[ql * TSTR + 512] * rv512;
    Out[((size_t)(b * SS + q0 + ql)) * DD + h * HD + d] = o / l;
  }
}

// ---- fallback (R2-style, used only if ws_size is too small) ----
#define FPSTR 1032
#define FVSTR 68
__global__ __launch_bounds__(256, 2)
void circ_attn_mfma(const float* __restrict__ Qg, const float* __restrict__ Kg,
                    const float* __restrict__ Vg, const float* __restrict__ Rkg,
                    const float* __restrict__ Rvg, float* __restrict__ Out) {
  __shared__ __align__(16) f16 Pf[QPB * FPSTR];
  __shared__ __align__(16) f16 Tb[QPB * TSTR];
  __shared__ __align__(16) f16 Sb[64 * KSTR];
  __shared__ __align__(16) f16 Qb[QPB * KSTR];
  __shared__ float lsw[4][16];
  const int bid = blockIdx.x;
  const int b = bid >> 10, h = (bid >> 6) & 15, q0 = (bid & 63) * QPB;
  const int tid = threadIdx.x, w = tid >> 6, lane = tid & 63;
  const int quad = lane >> 4, l16 = lane & 15;
  auto stage64 = [&](const float* src, int rstride, f16* dst, int dstr) {
    #pragma unroll
    for (int jj = 0; jj < 4; ++jj) {
      int i = jj * 256 + tid;
      int r = i >> 4, c = (i & 15) << 2;
      float4 v = *(const float4*)(src + (size_t)r * rstride + c);
      f16x4 hv; hv[0] = (f16)v.x; hv[1] = (f16)v.y; hv[2] = (f16)v.z; hv[3] = (f16)v.w;
      *(f16x4*)(dst + r * dstr + c) = hv;
    }
  };
  {
    int r = tid >> 4, c = (tid & 15) << 2;
    float4 v = *(const float4*)(Qg + (size_t)(b * SS + q0 + r) * DD + h * HD + c);
    f16x4 hv; hv[0] = (f16)v.x; hv[1] = (f16)v.y; hv[2] = (f16)v.z; hv[3] = (f16)v.w;
    *(f16x4*)(Qb + r * KSTR + c) = hv;
  }
  __syncthreads();
  const f16x8 qf0 = *(const f16x8*)(Qb + l16 * KSTR + quad * 8);
  const f16x8 qf1 = *(const f16x8*)(Qb + l16 * KSTR + 32 + quad * 8);
  #pragma unroll 1
  for (int cc = 0; cc < 8; ++cc) {
    stage64(Rkg + (size_t)(cc * 64) * HD, HD, Sb, KSTR);
    __syncthreads();
    f16x8 rk0 = *(const f16x8*)(Sb + (w * 16 + l16) * KSTR + quad * 8);
    f16x8 rk1 = *(const f16x8*)(Sb + (w * 16 + l16) * KSTR + 32 + quad * 8);
    f32x4 c = {0.f, 0.f, 0.f, 0.f};
    c = __builtin_amdgcn_mfma_f32_16x16x32_f16(qf0, rk0, c, 0, 0, 0);
    c = __builtin_amdgcn_mfma_f32_16x16x32_f16(qf1, rk1, c, 0, 0, 0);
    const int dbase = cc * 64 + w * 16 + l16;
    #pragma unroll
    for (int r = 0; r < 4; ++r) Tb[(quad * 4 + r) * TSTR + dbase] = (f16)c[r];
    __syncthreads();
  }
  if (w == 0) {
    float t = 0.f;
    #pragma unroll
    for (int i = 0; i < 16; ++i)
      t += (float)Qb[l16 * KSTR + quad * 16 + i] * Rkg[512 * HD + quad * 16 + i];
    t += __shfl_xor(t, 16); t += __shfl_xor(t, 32);
    if (quad == 0) Tb[l16 * TSTR + 512] = (f16)t;
  }
  float psum = 0.f;
  #pragma unroll 1
  for (int kc = 0; kc < 16; ++kc) {
    stage64(Kg + (size_t)(b * SS + kc * 64) * DD + h * HD, DD, Sb, KSTR);
    __syncthreads();
    f16x8 ka0 = *(const f16x8*)(Sb + (w * 16 + l16) * KSTR + quad * 8);
    f16x8 ka1 = *(const f16x8*)(Sb + (w * 16 + l16) * KSTR + 32 + quad * 8);
    f32x4 c = {0.f, 0.f, 0.f, 0.f};
    c = __builtin_amdgcn_mfma_f32_16x16x32_f16(ka0, qf0, c, 0, 0, 0);
    c = __builtin_amdgcn_mfma_f32_16x16x32_f16(ka1, qf1, c, 0, 0, 0);
    const int kb = kc * 64 + w * 16 + quad * 4;
    const int q = q0 + l16;
    f16x4 pv;
    #pragma unroll
    for (int r = 0; r < 4; ++r) {
      int key = kb + r;
      int j = (q - key) & 1023;
      int dist = (j < 1024 - j) ? j : 1024 - j;
      float s = c[r] * 0.125f + (float)Tb[l16 * TSTR + dist];
      float p = __expf(s);
      pv[r] = (f16)p;
      psum += p;
    }
    *(f16x4*)(Pf + l16 * FPSTR + kb) = pv;
    __syncthreads();
  }
  psum += __shfl_xor(psum, 16); psum += __shfl_xor(psum, 32);
  if (quad == 0) lsw[w][l16] = psum;
  f32x4 co = {0.f, 0.f, 0.f, 0.f};
  const int d = w * 16 + l16;
  #pragma unroll 1
  for (int kc = 0; kc < 16; ++kc) {
    stage64(Vg + (size_t)(b * SS + kc * 64) * DD + h * HD, DD, Sb, FVSTR);
    __syncthreads();
    #pragma unroll
    for (int kd = 0; kd < 2; ++kd) {
      f16x8 bv;
      #pragma unroll
      for (int j = 0; j < 8; ++j) bv[j] = Sb[(kd * 32 + quad * 8 + j) * FVSTR + d];
      f16x8 ap = *(const f16x8*)(Pf + l16 * FPSTR + kc * 64 + kd * 32 + quad * 8);
      co = __builtin_amdgcn_mfma_f32_16x16x32_f16(ap, bv, co, 0, 0, 0);
    }
    __syncthreads();
  }
  #pragma unroll 1
  for (int i = tid; i < QPB * 513; i += 256) {
    int ql = i / 513, dist = i - ql * 513, q = q0 + ql;
    int k1 = (q - dist) & 1023;
    float wv = (float)Pf[ql * FPSTR + k1];
    if (dist != 0 && dist != 512) wv += (float)Pf[ql * FPSTR + ((q + dist) & 1023)];
    Tb[ql * TSTR + dist] = (f16)wv;
  }
  __syncthreads();
  #pragma unroll 1
  for (int cc = 0; cc < 8; ++cc) {
    stage64(Rvg + (size_t)(cc * 64) * HD, HD, Sb, FVSTR);
    __syncthreads();
    #pragma unroll
    for (int kd = 0; kd < 2; ++kd) {
      f16x8 bv;
      #pragma unroll
      for (int j = 0; j < 8; ++j) bv[j] = Sb[(kd * 32 + quad * 8 + j) * FVSTR + d];
      f16x8 aw = *(const f16x8*)(Tb + l16 * TSTR + cc * 64 + kd * 32 + quad * 8);
      co = __builtin_amdgcn_mfma_f32_16x16x32_f16(aw, bv, co, 0, 0, 0);
    }
    __syncthreads();
  }
  const float rv512 = Rvg[512 * HD + d];
  #pragma unroll
  for (int r = 0; r < 4; ++r) {
    int ql = quad * 4 + r;
    float l = lsw[0][ql] + lsw[1][ql] + lsw[2][ql] + lsw[3][ql];
    float o = co[r] + (float)Tb[ql * TSTR + 512] * rv512;
    Out[(size_t)(b * SS + q0 + ql) * DD + h * HD + d] = o / l;
  }
}

extern "C" void kernel_launch(void* const* d_in, const int* in_sizes, int n_in,
                              void* d_out, int out_size, void* d_ws, size_t ws_size,
                              hipStream_t stream) {
  const float* q  = (const float*)d_in[0];
  const float* k  = (const float*)d_in[1];
  const float* v  = (const float*)d_in[2];
  const float* rk = (const float*)d_in[3];
  const float* rv = (const float*)d_in[4];
  float* out = (float*)d_out;
  const int nblocks = BB * HH * (SS / QPB);  // 8192
  if (ws_size >= WS_NEED) {
    f16* vt  = (f16*)d_ws;
    f16* rvt = vt + VT_ELEMS;
    prep_kernel<<<dim3(2048 + 8), dim3(256), 0, stream>>>(v, rv, vt, rvt);
    circ_attn_v4<<<dim3(nblocks), dim3(256), 0, stream>>>(q, k, rk, rv, vt, rvt, out);
  } else {
    circ_attn_mfma<<<dim3(nblocks), dim3(256), 0, stream>>>(q, k, v, rk, rv, out);
  }
}

// Round 6
// 486.835 us; speedup vs baseline: 8.3710x; 1.2846x over previous
//
#include <hip/hip_runtime.h>

typedef _Float16 f16;
typedef __attribute__((ext_vector_type(4))) _Float16 f16x4;
typedef __attribute__((ext_vector_type(8))) _Float16 f16x8;
typedef __attribute__((ext_vector_type(4))) float f32x4;

#define BB 8
#define SS 1024
#define DD 1024
#define HH 16
#define HD 64
#define QPB 16
#define PROW 1040   // Pf row len (f16): 2080 B rows (16B-aligned); cols 0..1023 + 8-pad
#define TSTR 520    // T/W row stride (f16): 1040 B = 65*16 (16B-aligned rows)
#define KSTR 72     // prep-kernel LDS staging stride
#define RVSTR 520   // Rvt global row stride (f16)

#define VT_ELEMS  ((size_t)BB * HH * HD * SS)   // 8,388,608
#define RVT_ELEMS ((size_t)HD * RVSTR)          // 33,280
#define RKT_ELEMS ((size_t)513 * HD)            // 32,832
#define KT_ELEMS  ((size_t)BB * HH * SS * HD)   // 8,388,608
#define WS_PART ((VT_ELEMS + RVT_ELEMS + RKT_ELEMS) * 2)
#define WS_FULL ((VT_ELEMS + RVT_ELEMS + RKT_ELEMS + KT_ELEMS) * 2)

__device__ inline f16x8 cvt16(float4 a, float4 b) {
  f16x8 h;
  h[0] = (f16)a.x; h[1] = (f16)a.y; h[2] = (f16)a.z; h[3] = (f16)a.w;
  h[4] = (f16)b.x; h[5] = (f16)b.y; h[6] = (f16)b.z; h[7] = (f16)b.w;
  return h;
}

// ---- prep: Vt[b][h][d][s], Rvt[d][dist] (transposes), Kt[b][h][s][d], Rkt f16 casts ----
__global__ __launch_bounds__(256, 2)
void prep_kernel(const float* __restrict__ Vg, const float* __restrict__ Rvg,
                 const float* __restrict__ Kg, const float* __restrict__ Rkg,
                 f16* __restrict__ Vt, f16* __restrict__ Rvt,
                 f16* __restrict__ Rkt, f16* __restrict__ Kt) {
  __shared__ __align__(16) f16 Tt[64 * KSTR];
  const int tid = threadIdx.x;
  const int bid = blockIdx.x;

  if (bid < 2056) {  // transpose sections (V, Rv)
    const int sr = tid >> 2, cs = (tid & 3) * 16;
    const float* src;
    int srcstride;
    f16* dst;
    int dststride, dstcol;
    if (bid < 2048) {
      int b = bid >> 8, h = (bid >> 4) & 15, tc = bid & 15;
      src = Vg + ((size_t)(b * SS + tc * 64)) * DD + h * HD;
      srcstride = DD;
      dst = Vt + ((size_t)((b * HH + h) * HD)) * SS;
      dststride = SS; dstcol = tc * 64;
    } else {
      int cc = bid - 2048;                       // 0..7, dists 0..511
      src = Rvg + ((size_t)(cc * 64)) * HD;
      srcstride = HD;
      dst = Rvt;
      dststride = RVSTR; dstcol = cc * 64;
    }
    {
      const float* s = src + (size_t)sr * srcstride + cs;
      float4 v0 = *(const float4*)(s);
      float4 v1 = *(const float4*)(s + 4);
      float4 v2 = *(const float4*)(s + 8);
      float4 v3 = *(const float4*)(s + 12);
      *(f16x8*)(Tt + sr * KSTR + cs) = cvt16(v0, v1);
      *(f16x8*)(Tt + sr * KSTR + cs + 8) = cvt16(v2, v3);
    }
    __syncthreads();
    {
      f16x8 o0, o1;
      #pragma unroll
      for (int i = 0; i < 8; ++i) o0[i] = Tt[(cs + i) * KSTR + sr];
      #pragma unroll
      for (int i = 0; i < 8; ++i) o1[i] = Tt[(cs + 8 + i) * KSTR + sr];
      f16* o = dst + (size_t)sr * dststride + dstcol + cs;
      *(f16x8*)(o) = o0;
      *(f16x8*)(o + 8) = o1;
    }
  } else if (bid < 2058) {  // Rk cast: 513*64 = 32832 elems, 2 blocks
    const int base = (bid - 2056) * 16416;
    for (int j = tid; j < 16416; j += 256)
      Rkt[base + j] = (f16)Rkg[base + j];
  } else {
    // K cast -> Kt[b][h][s][d]: 2048 blocks x 4 iters x 256 thr = 2,097,152 float4
    // (= 8,388,608 elements exactly; R5 bug was 8 iters -> 2x OOB on Kg/Kt)
    const int n = bid - 2058;
    #pragma unroll
    for (int jj = 0; jj < 4; ++jj) {
      int o4 = n * 1024 + jj * 256 + tid;
      int d4 = o4 & 15;
      int s  = (o4 >> 4) & 1023;
      int bh = o4 >> 14;                 // 0..127
      int b = bh >> 4, h = bh & 15;
      float4 v = *(const float4*)(Kg + ((size_t)(b * SS + s)) * DD + h * HD + d4 * 4);
      f16x4 hv; hv[0] = (f16)v.x; hv[1] = (f16)v.y; hv[2] = (f16)v.z; hv[3] = (f16)v.w;
      *(f16x4*)(Kt + (size_t)o4 * 4) = hv;
    }
  }
}

// ---- main v5: LDS = Pf 33280 + Tb 16640 + lsw 256 = 50176 B -> 3 blocks/CU.
// f16 operands from ws, 2-deep prefetch, vectorized W gather, XCD swizzle.
template <bool KT16>
__global__ __launch_bounds__(256, 3)
void circ_attn_v5(const float* __restrict__ Qg, const float* __restrict__ Kg,
                  const f16* __restrict__ Kt, const f16* __restrict__ Rkt,
                  const float* __restrict__ Rkg, const float* __restrict__ Rvg,
                  const f16* __restrict__ Vt, const f16* __restrict__ Rvt,
                  float* __restrict__ Out) {
  __shared__ __align__(16) f16 Pf[QPB * PROW];
  __shared__ __align__(16) f16 Tb[QPB * TSTR];   // bias table T, later reused as W
  __shared__ float lsw[4][16];

  // XCD swizzle: all 64 q-blocks of one (b,h) land on XCD (g & 7)
  const int i = blockIdx.x;
  const int g = ((i >> 9) << 3) | (i & 7);   // (b,h) group 0..127
  const int m = (i >> 3) & 63;               // q-block 0..63
  const int b = g >> 4;
  const int h = g & 15;
  const int q0 = m * QPB;

  const int tid = threadIdx.x;
  const int w = tid >> 6;
  const int lane = tid & 63;
  const int quad = lane >> 4;
  const int l16 = lane & 15;

  // ---- Q fragments straight from global (A-layout == B-layout) ----
  f16x8 qf0, qf1;
  {
    const float* qrow = Qg + ((size_t)(b * SS + q0 + l16)) * DD + h * HD;
    float4 a0 = *(const float4*)(qrow + quad * 8);
    float4 a1 = *(const float4*)(qrow + quad * 8 + 4);
    float4 a2 = *(const float4*)(qrow + 32 + quad * 8);
    float4 a3 = *(const float4*)(qrow + 32 + quad * 8 + 4);
    qf0 = cvt16(a0, a1);
    qf1 = cvt16(a2, a3);
  }

  // ---- Phase T: T[q][dist] = Q . Rk^T (dists 0..511), f16 B-frags, 1-deep PF ----
  {
    const f16* rkp = Rkt + ((size_t)(w * 16 + l16)) * HD + quad * 8;
    f16x8 t0 = *(const f16x8*)(rkp);
    f16x8 t1 = *(const f16x8*)(rkp + 32);
    #pragma unroll 2
    for (int cc = 0; cc < 8; ++cc) {
      f16x8 c0 = t0, c1 = t1;
      if (cc < 7) {
        const f16* np = rkp + (size_t)(cc + 1) * 64 * HD;
        t0 = *(const f16x8*)(np);
        t1 = *(const f16x8*)(np + 32);
      }
      f32x4 c = {0.f, 0.f, 0.f, 0.f};
      c = __builtin_amdgcn_mfma_f32_16x16x32_f16(qf0, c0, c, 0, 0, 0);
      c = __builtin_amdgcn_mfma_f32_16x16x32_f16(qf1, c1, c, 0, 0, 0);
      const int dbase = cc * 64 + w * 16 + l16;
      #pragma unroll
      for (int r = 0; r < 4; ++r)
        Tb[(quad * 4 + r) * TSTR + dbase] = (f16)c[r];
    }
  }
  // dist 512 (wave 0 only, f32 path)
  if (w == 0) {
    const float* rk = Rkg + 512 * HD;
    float t = 0.f;
    #pragma unroll
    for (int j = 0; j < 8; ++j) t += (float)qf0[j] * rk[quad * 8 + j];
    #pragma unroll
    for (int j = 0; j < 8; ++j) t += (float)qf1[j] * rk[32 + quad * 8 + j];
    t += __shfl_xor(t, 16);
    t += __shfl_xor(t, 32);
    if (quad == 0) Tb[l16 * TSTR + 512] = (f16)t;
  }

  // Phase A initial K prefetch (issued before barrier; independent of Tb)
  const f16* kp16 = KT16 ?
      (Kt + (((size_t)(b * HH + h) << 10) + w * 16 + l16) * HD + quad * 8) : nullptr;
  const float* kp32 = KT16 ? nullptr :
      (Kg + ((size_t)(b * SS + w * 16 + l16)) * DD + h * HD + quad * 8);
  f16x8 ka0, ka1, kb0, kb1;
  float4 f0, f1, f2, f3;
  if (KT16) {
    ka0 = *(const f16x8*)(kp16);
    ka1 = *(const f16x8*)(kp16 + 32);
    kb0 = *(const f16x8*)(kp16 + 64 * HD);
    kb1 = *(const f16x8*)(kp16 + 64 * HD + 32);
  } else {
    f0 = *(const float4*)(kp32);
    f1 = *(const float4*)(kp32 + 4);
    f2 = *(const float4*)(kp32 + 32);
    f3 = *(const float4*)(kp32 + 36);
  }
  __syncthreads();   // barrier 1: Tb(T) ready

  // ---- Phase A: S^T = K . Q^T ; early Tb gathers, exp -> Pf ----
  {
    float psum = 0.f;
    #pragma unroll 2
    for (int kc = 0; kc < 16; ++kc) {
      f16x8 c0, c1;
      if (KT16) {
        c0 = ka0; c1 = ka1; ka0 = kb0; ka1 = kb1;
        if (kc < 14) {
          const f16* np = kp16 + (size_t)(kc + 2) * 64 * HD;
          kb0 = *(const f16x8*)(np);
          kb1 = *(const f16x8*)(np + 32);
        }
      } else {
        c0 = cvt16(f0, f1); c1 = cvt16(f2, f3);
        if (kc < 15) {
          const float* s = kp32 + (size_t)(kc + 1) * 64 * DD;
          f0 = *(const float4*)(s);     f1 = *(const float4*)(s + 4);
          f2 = *(const float4*)(s + 32); f3 = *(const float4*)(s + 36);
        }
      }
      // bias gathers (independent of MFMA result -> issued early)
      const int kb_ = kc * 64 + w * 16 + quad * 4;
      const int q = q0 + l16;
      const int j0 = (q - kb_) & 1023;
      float tv[4];
      #pragma unroll
      for (int r = 0; r < 4; ++r) {
        int jr = (j0 - r) & 1023;
        int dist = (jr < 1024 - jr) ? jr : 1024 - jr;
        tv[r] = (float)Tb[l16 * TSTR + dist];
      }
      f32x4 c = {0.f, 0.f, 0.f, 0.f};
      c = __builtin_amdgcn_mfma_f32_16x16x32_f16(c0, qf0, c, 0, 0, 0);
      c = __builtin_amdgcn_mfma_f32_16x16x32_f16(c1, qf1, c, 0, 0, 0);
      f16x4 pv;
      #pragma unroll
      for (int r = 0; r < 4; ++r) {
        float s = fmaf(c[r], 0.125f, tv[r]);
        float p = __expf(s);            // no max-subtract: |s| small, fp32-safe
        pv[r] = (f16)p;
        psum += p;
      }
      *(f16x4*)(Pf + l16 * PROW + kb_) = pv;
    }
    psum += __shfl_xor(psum, 16);
    psum += __shfl_xor(psum, 32);
    if (quad == 0) lsw[w][l16] = psum;
  }
  // circular pad: Pf[q][1024..1031] = Pf[q][0..7] (wave 0 wrote cols 0..7)
  if (w == 0 && lane < 16)
    *(f16x8*)(Pf + lane * PROW + 1024) = *(const f16x8*)(Pf + lane * PROW);

  // Phase B initial V prefetch (independent of Pf)
  const f16* vtp = Vt + ((size_t)((b * HH + h) * HD) + w * 16 + l16) * SS + quad * 8;
  f16x8 va0 = *(const f16x8*)(vtp);
  f16x8 va1 = *(const f16x8*)(vtp + 32);
  f16x8 vb0 = *(const f16x8*)(vtp + 64);
  f16x8 vb1 = *(const f16x8*)(vtp + 96);
  __syncthreads();   // barrier 2: Pf + pad + lsw ready

  // ---- Phase B: O = P . V ; wave w owns d-columns [w*16, w*16+16) ----
  f32x4 co = {0.f, 0.f, 0.f, 0.f};
  {
    #pragma unroll 2
    for (int kc = 0; kc < 16; ++kc) {
      f16x8 cb0 = va0, cb1 = va1;
      va0 = vb0; va1 = vb1;
      if (kc < 14) {
        const f16* s = vtp + (kc + 2) * 64;
        vb0 = *(const f16x8*)(s);
        vb1 = *(const f16x8*)(s + 32);
      }
      f16x8 ap0 = *(const f16x8*)(Pf + l16 * PROW + kc * 64 + quad * 8);
      f16x8 ap1 = *(const f16x8*)(Pf + l16 * PROW + kc * 64 + 32 + quad * 8);
      co = __builtin_amdgcn_mfma_f32_16x16x32_f16(ap0, cb0, co, 0, 0, 0);
      co = __builtin_amdgcn_mfma_f32_16x16x32_f16(ap1, cb1, co, 0, 0, 0);
    }
  }

  // ---- Phase W (vectorized): per lane 4 window-iters over (row, 8-dist group) ----
  #pragma unroll
  for (int it = 0; it < 4; ++it) {
    const int flat = it * 256 + tid;   // whole wave shares one row ql
    const int ql = flat >> 6;
    const int gg = flat & 63;          // dist group: dists gg*8 .. gg*8+7
    const int qq = q0 + ql;
    const int bm = (qq - 8 * gg - 7) & 1023;
    const int bp = (qq + 8 * gg) & 1023;
    const f16* rowp = Pf + ql * PROW;
    f16 mv[8], pv2[8];
    #pragma unroll
    for (int j = 0; j < 8; ++j) mv[j] = rowp[bm + j];
    #pragma unroll
    for (int j = 0; j < 8; ++j) pv2[j] = rowp[bp + j];
    f16x8 wv;
    #pragma unroll
    for (int j = 0; j < 8; ++j) wv[j] = (f16)((float)mv[7 - j] + (float)pv2[j]);
    if (gg == 0) wv[0] = mv[7];        // dist 0: single term P[q]
    *(f16x8*)(Tb + ql * TSTR + gg * 8) = wv;
  }
  if (tid < 16)                        // dist 512: single term P[(q+512) mod S]
    Tb[tid * TSTR + 512] = Pf[tid * PROW + ((q0 + tid + 512) & 1023)];

  // Wrelv initial Rv prefetch (independent of W)
  const f16* rvp = Rvt + ((size_t)(w * 16 + l16)) * RVSTR + quad * 8;
  f16x8 r0 = *(const f16x8*)(rvp);
  f16x8 r1 = *(const f16x8*)(rvp + 32);
  __syncthreads();   // barrier 3: W ready

  // ---- Phase Wrelv: co += W . Rv (dists 0..511) ----
  {
    #pragma unroll 2
    for (int cc = 0; cc < 8; ++cc) {
      f16x8 cb0 = r0, cb1 = r1;
      if (cc < 7) {
        const f16* s = rvp + (cc + 1) * 64;
        r0 = *(const f16x8*)(s);
        r1 = *(const f16x8*)(s + 32);
      }
      f16x8 aw0 = *(const f16x8*)(Tb + l16 * TSTR + cc * 64 + quad * 8);
      f16x8 aw1 = *(const f16x8*)(Tb + l16 * TSTR + cc * 64 + 32 + quad * 8);
      co = __builtin_amdgcn_mfma_f32_16x16x32_f16(aw0, cb0, co, 0, 0, 0);
      co = __builtin_amdgcn_mfma_f32_16x16x32_f16(aw1, cb1, co, 0, 0, 0);
    }
  }

  // ---- finalize: dist-512 rel_v term + normalize + store ----
  const int d = w * 16 + l16;
  const float rv512 = Rvg[512 * HD + d];
  #pragma unroll
  for (int r = 0; r < 4; ++r) {
    int ql = quad * 4 + r;
    float l = lsw[0][ql] + lsw[1][ql] + lsw[2][ql] + lsw[3][ql];
    float o = co[r] + (float)Tb[ql * TSTR + 512] * rv512;
    Out[((size_t)(b * SS + q0 + ql)) * DD + h * HD + d] = o / l;
  }
}

// ---- fallback (R2-style, used only if ws_size is tiny) ----
#define FPSTR 1032
#define FVSTR 68
__global__ __launch_bounds__(256, 2)
void circ_attn_mfma(const float* __restrict__ Qg, const float* __restrict__ Kg,
                    const float* __restrict__ Vg, const float* __restrict__ Rkg,
                    const float* __restrict__ Rvg, float* __restrict__ Out) {
  __shared__ __align__(16) f16 Pf[QPB * FPSTR];
  __shared__ __align__(16) f16 Tb[QPB * TSTR];
  __shared__ __align__(16) f16 Sb[64 * KSTR];
  __shared__ __align__(16) f16 Qb[QPB * KSTR];
  __shared__ float lsw[4][16];
  const int bid = blockIdx.x;
  const int b = bid >> 10, h = (bid >> 6) & 15, q0 = (bid & 63) * QPB;
  const int tid = threadIdx.x, w = tid >> 6, lane = tid & 63;
  const int quad = lane >> 4, l16 = lane & 15;
  auto stage64 = [&](const float* src, int rstride, f16* dst, int dstr) {
    #pragma unroll
    for (int jj = 0; jj < 4; ++jj) {
      int i = jj * 256 + tid;
      int r = i >> 4, c = (i & 15) << 2;
      float4 v = *(const float4*)(src + (size_t)r * rstride + c);
      f16x4 hv; hv[0] = (f16)v.x; hv[1] = (f16)v.y; hv[2] = (f16)v.z; hv[3] = (f16)v.w;
      *(f16x4*)(dst + r * dstr + c) = hv;
    }
  };
  {
    int r = tid >> 4, c = (tid & 15) << 2;
    float4 v = *(const float4*)(Qg + (size_t)(b * SS + q0 + r) * DD + h * HD + c);
    f16x4 hv; hv[0] = (f16)v.x; hv[1] = (f16)v.y; hv[2] = (f16)v.z; hv[3] = (f16)v.w;
    *(f16x4*)(Qb + r * KSTR + c) = hv;
  }
  __syncthreads();
  const f16x8 qf0 = *(const f16x8*)(Qb + l16 * KSTR + quad * 8);
  const f16x8 qf1 = *(const f16x8*)(Qb + l16 * KSTR + 32 + quad * 8);
  #pragma unroll 1
  for (int cc = 0; cc < 8; ++cc) {
    stage64(Rkg + (size_t)(cc * 64) * HD, HD, Sb, KSTR);
    __syncthreads();
    f16x8 rk0 = *(const f16x8*)(Sb + (w * 16 + l16) * KSTR + quad * 8);
    f16x8 rk1 = *(const f16x8*)(Sb + (w * 16 + l16) * KSTR + 32 + quad * 8);
    f32x4 c = {0.f, 0.f, 0.f, 0.f};
    c = __builtin_amdgcn_mfma_f32_16x16x32_f16(qf0, rk0, c, 0, 0, 0);
    c = __builtin_amdgcn_mfma_f32_16x16x32_f16(qf1, rk1, c, 0, 0, 0);
    const int dbase = cc * 64 + w * 16 + l16;
    #pragma unroll
    for (int r = 0; r < 4; ++r) Tb[(quad * 4 + r) * TSTR + dbase] = (f16)c[r];
    __syncthreads();
  }
  if (w == 0) {
    float t = 0.f;
    #pragma unroll
    for (int i = 0; i < 16; ++i)
      t += (float)Qb[l16 * KSTR + quad * 16 + i] * Rkg[512 * HD + quad * 16 + i];
    t += __shfl_xor(t, 16); t += __shfl_xor(t, 32);
    if (quad == 0) Tb[l16 * TSTR + 512] = (f16)t;
  }
  float psum = 0.f;
  #pragma unroll 1
  for (int kc = 0; kc < 16; ++kc) {
    stage64(Kg + (size_t)(b * SS + kc * 64) * DD + h * HD, DD, Sb, KSTR);
    __syncthreads();
    f16x8 ka0 = *(const f16x8*)(Sb + (w * 16 + l16) * KSTR + quad * 8);
    f16x8 ka1 = *(const f16x8*)(Sb + (w * 16 + l16) * KSTR + 32 + quad * 8);
    f32x4 c = {0.f, 0.f, 0.f, 0.f};
    c = __builtin_amdgcn_mfma_f32_16x16x32_f16(ka0, qf0, c, 0, 0, 0);
    c = __builtin_amdgcn_mfma_f32_16x16x32_f16(ka1, qf1, c, 0, 0, 0);
    const int kb = kc * 64 + w * 16 + quad * 4;
    const int q = q0 + l16;
    f16x4 pv;
    #pragma unroll
    for (int r = 0; r < 4; ++r) {
      int key = kb + r;
      int j = (q - key) & 1023;
      int dist = (j < 1024 - j) ? j : 1024 - j;
      float s = c[r] * 0.125f + (float)Tb[l16 * TSTR + dist];
      float p = __expf(s);
      pv[r] = (f16)p;
      psum += p;
    }
    *(f16x4*)(Pf + l16 * FPSTR + kb) = pv;
    __syncthreads();
  }
  psum += __shfl_xor(psum, 16); psum += __shfl_xor(psum, 32);
  if (quad == 0) lsw[w][l16] = psum;
  f32x4 co = {0.f, 0.f, 0.f, 0.f};
  const int d = w * 16 + l16;
  #pragma unroll 1
  for (int kc = 0; kc < 16; ++kc) {
    stage64(Vg + (size_t)(b * SS + kc * 64) * DD + h * HD, DD, Sb, FVSTR);
    __syncthreads();
    #pragma unroll
    for (int kd = 0; kd < 2; ++kd) {
      f16x8 bv;
      #pragma unroll
      for (int j = 0; j < 8; ++j) bv[j] = Sb[(kd * 32 + quad * 8 + j) * FVSTR + d];
      f16x8 ap = *(const f16x8*)(Pf + l16 * FPSTR + kc * 64 + kd * 32 + quad * 8);
      co = __builtin_amdgcn_mfma_f32_16x16x32_f16(ap, bv, co, 0, 0, 0);
    }
    __syncthreads();
  }
  #pragma unroll 1
  for (int i = tid; i < QPB * 513; i += 256) {
    int ql = i / 513, dist = i - ql * 513, q = q0 + ql;
    int k1 = (q - dist) & 1023;
    float wv = (float)Pf[ql * FPSTR + k1];
    if (dist != 0 && dist != 512) wv += (float)Pf[ql * FPSTR + ((q + dist) & 1023)];
    Tb[ql * TSTR + dist] = (f16)wv;
  }
  __syncthreads();
  #pragma unroll 1
  for (int cc = 0; cc < 8; ++cc) {
    stage64(Rvg + (size_t)(cc * 64) * HD, HD, Sb, FVSTR);
    __syncthreads();
    #pragma unroll
    for (int kd = 0; kd < 2; ++kd) {
      f16x8 bv;
      #pragma unroll
      for (int j = 0; j < 8; ++j) bv[j] = Sb[(kd * 32 + quad * 8 + j) * FVSTR + d];
      f16x8 aw = *(const f16x8*)(Tb + l16 * TSTR + cc * 64 + kd * 32 + quad * 8);
      co = __builtin_amdgcn_mfma_f32_16x16x32_f16(aw, bv, co, 0, 0, 0);
    }
    __syncthreads();
  }
  const float rv512 = Rvg[512 * HD + d];
  #pragma unroll
  for (int r = 0; r < 4; ++r) {
    int ql = quad * 4 + r;
    float l = lsw[0][ql] + lsw[1][ql] + lsw[2][ql] + lsw[3][ql];
    float o = co[r] + (float)Tb[ql * TSTR + 512] * rv512;
    Out[(size_t)(b * SS + q0 + ql) * DD + h * HD + d] = o / l;
  }
}

extern "C" void kernel_launch(void* const* d_in, const int* in_sizes, int n_in,
                              void* d_out, int out_size, void* d_ws, size_t ws_size,
                              hipStream_t stream) {
  const float* q  = (const float*)d_in[0];
  const float* k  = (const float*)d_in[1];
  const float* v  = (const float*)d_in[2];
  const float* rk = (const float*)d_in[3];
  const float* rv = (const float*)d_in[4];
  float* out = (float*)d_out;
  const int nblocks = BB * HH * (SS / QPB);  // 8192
  f16* vt  = (f16*)d_ws;
  f16* rvt = vt + VT_ELEMS;
  f16* rkt = rvt + RVT_ELEMS;
  f16* kt  = rkt + RKT_ELEMS;
  if (ws_size >= WS_FULL) {
    prep_kernel<<<dim3(2058 + 2048), dim3(256), 0, stream>>>(v, rv, k, rk, vt, rvt, rkt, kt);
    circ_attn_v5<true><<<dim3(nblocks), dim3(256), 0, stream>>>(
        q, k, kt, rkt, rk, rv, vt, rvt, out);
  } else if (ws_size >= WS_PART) {
    prep_kernel<<<dim3(2058), dim3(256), 0, stream>>>(v, rv, k, rk, vt, rvt, rkt, kt);
    circ_attn_v5<false><<<dim3(nblocks), dim3(256), 0, stream>>>(
        q, k, kt, rkt, rk, rv, vt, rvt, out);
  } else {
    circ_attn_mfma<<<dim3(nblocks), dim3(256), 0, stream>>>(q, k, v, rk, rv, out);
  }
}